// Round 5
// baseline (1381.695 us; speedup 1.0000x reference)
//
#include <hip/hip_runtime.h>
#include <hip/hip_bf16.h>

#define NN 100000     // nodes
#define NE 3200000    // edges
#define NG 512        // graphs
#define IND 128
#define H1D 32
#define H2D 16

#define BK   128              // nodes per bucket
#define NBUK 782              // ceil(NN/BK)
#define CAP  4864             // slots per bucket (mean 4096; +8 sigma + 256-pad + prefetch slack)
#define DUMMY NN              // dummy src row (zeroed); localdst bits = 0
#define S1 33                 // padded LDS stride for H1D rows
#define S2 17                 // padded LDS stride for H2D rows

// ---------------- workspace layout (element offsets, 4B each) ----------------
#define O_BCUR  0u            // int[1024]
#define O_GSUM  1024u         // float[512]
#define O_GCNT  1536u         // float[512]
#define O_DINV  2048u         // float[100352]
#define O_PAIRS 102400u       // int[NBUK*CAP = 3,803,648] packed: src | (localdst<<17)
#define O_H1S   3906048u      // float[(NN+1)*32]  h1s = (x@W1)*dinv, +1 dummy row
#define O_H2S   7106080u      // float[(NN+1)*16]  h2s = (feat1@W2)*dinv, +1 dummy row
// total = 8,706,096 elems = 34.8 MB

__device__ __forceinline__ void load_lds16(const float* g, float* l) {
    // fire-and-forget global->LDS DMA: no result VGPR, vmcnt-counted.
    // LDS dest = wave-uniform base; lane i's 16B lands at base + i*16.
    __builtin_amdgcn_global_load_lds(
        (const __attribute__((address_space(1))) void*)g,
        (__attribute__((address_space(3))) void*)l, 16, 0, 0);
}

__global__ __launch_bounds__(256) void k_init(int* bcur, float* gsum, float* gcnt,
                                              float* h1s, float* h2s) {
    int i = blockIdx.x * 256 + threadIdx.x;
    if (i < 1024) bcur[i] = i * CAP;
    if (i < NG) { gsum[i] = 0.f; gcnt[i] = 0.f; }
    if (i < H1D) h1s[(size_t)NN * H1D + i] = 0.f;   // dummy row for padded edges
    if (i < H2D) h2s[(size_t)NN * H2D + i] = 0.f;
}

// Stage edges into per-bucket regions. Tile = 4096 edges per block; LDS binning
// + one bulk cursor atomic per (block,bucket) -> writes are sequential runs.
__global__ __launch_bounds__(256) void k_stage(const int* __restrict__ src,
                                               const int* __restrict__ dst,
                                               int* bcur, int* __restrict__ pairs) {
    __shared__ int cnt[NBUK], pre[NBUK], cur[NBUK], gb[NBUK];
    __shared__ int2 buf[4096];     // (packed, bucket)
    __shared__ int scan[256];
    int t = threadIdx.x;
    for (int i = t; i < NBUK; i += 256) cnt[i] = 0;
    __syncthreads();

    int eb = blockIdx.x * 4096;
    int s16[16], d16[16];
#pragma unroll
    for (int j = 0; j < 16; ++j) {
        int e = eb + j * 256 + t;
        if (e < NE) {
            s16[j] = src[e];
            d16[j] = dst[e];
            atomicAdd(&cnt[d16[j] >> 7], 1);
        } else d16[j] = -1;
    }
    __syncthreads();

    int c0 = (t * 4 + 0 < NBUK) ? cnt[t * 4 + 0] : 0;
    int c1 = (t * 4 + 1 < NBUK) ? cnt[t * 4 + 1] : 0;
    int c2 = (t * 4 + 2 < NBUK) ? cnt[t * 4 + 2] : 0;
    int c3 = (t * 4 + 3 < NBUK) ? cnt[t * 4 + 3] : 0;
    int s4 = c0 + c1 + c2 + c3;
    scan[t] = s4;
    __syncthreads();
    for (int off = 1; off < 256; off <<= 1) {
        int v = (t >= off) ? scan[t - off] : 0;
        __syncthreads();
        scan[t] += v;
        __syncthreads();
    }
    int excl = scan[t] - s4;
    if (t * 4 + 0 < NBUK) pre[t * 4 + 0] = excl;
    if (t * 4 + 1 < NBUK) pre[t * 4 + 1] = excl + c0;
    if (t * 4 + 2 < NBUK) pre[t * 4 + 2] = excl + c0 + c1;
    if (t * 4 + 3 < NBUK) pre[t * 4 + 3] = excl + c0 + c1 + c2;
    __syncthreads();

    for (int i = t; i < NBUK; i += 256) {
        int c = cnt[i];
        gb[i] = c ? atomicAdd(&bcur[i], c) : 0;
        cur[i] = pre[i];
    }
    __syncthreads();

#pragma unroll
    for (int j = 0; j < 16; ++j) {
        if (d16[j] >= 0) {
            int b = d16[j] >> 7;
            int slot = atomicAdd(&cur[b], 1);
            buf[slot] = make_int2(s16[j] | ((d16[j] & 127) << 17), b);
        }
    }
    __syncthreads();

    int tot = scan[255];
    for (int slot = t; slot < tot; slot += 256) {
        int2 e = buf[slot];
        pairs[gb[e.y] + (slot - pre[e.y])] = e.x;
    }
}

// per-bucket degree histogram -> dinv; graph node counts; pad bucket to mult-of-256
__global__ __launch_bounds__(256) void k_deg(const int* __restrict__ bcur,
                                             int* __restrict__ pairs,
                                             const int* __restrict__ batch,
                                             float* __restrict__ dinv,
                                             float* gcnt) {
    __shared__ int hist[BK];
    int t = threadIdx.x, b = blockIdx.x;
    if (t < BK) hist[t] = 0;
    __syncthreads();
    int cnt = bcur[b] - b * CAP;
    int cnt_pad = (cnt + 255) & ~255;
    for (int i = cnt + t; i < cnt_pad; i += 256) pairs[(size_t)b * CAP + i] = DUMMY;
    const int* pb = pairs + (size_t)b * CAP;
    for (int i = t; i < cnt; i += 256) atomicAdd(&hist[pb[i] >> 17], 1);
    __syncthreads();
    if (t < BK) {
        int d = b * BK + t;
        if (d < NN) {
            dinv[d] = rsqrtf((float)(hist[t] + 1));   // +1 self-loop
            atomicAdd(&gcnt[batch[d]], 1.0f);
        }
    }
}

// h1s = (x @ W1) * dinv : register-tiled 2 nodes x 4 k per thread
__global__ __launch_bounds__(256) void k_gemm1(const float* __restrict__ x,
                                               const float* __restrict__ W1,
                                               const float* __restrict__ dinv,
                                               float* __restrict__ h1s) {
    __shared__ float sX[64][IND + 1];
    __shared__ float sW[IND * H1D];
    int t = threadIdx.x;
    int nodeBase = blockIdx.x * 64;
    for (int i = t; i < IND * H1D; i += 256) sW[i] = W1[i];
    for (int i = t; i < 64 * IND / 4; i += 256) {
        int r = i >> 5;
        int c = (i & 31) * 4;
        int d = nodeBase + r;
        float4 v = (d < NN) ? *(const float4*)&x[(size_t)d * IND + c]
                            : make_float4(0.f, 0.f, 0.f, 0.f);
        sX[r][c] = v.x; sX[r][c + 1] = v.y; sX[r][c + 2] = v.z; sX[r][c + 3] = v.w;
    }
    __syncthreads();
    int k0 = (t & 7) * 4;
    int n0 = (t >> 3) * 2;
    float a00 = 0, a01 = 0, a02 = 0, a03 = 0, a10 = 0, a11 = 0, a12 = 0, a13 = 0;
#pragma unroll 4
    for (int i = 0; i < IND; ++i) {
        float4 w = *(const float4*)&sW[i * H1D + k0];
        float x0 = sX[n0][i], x1 = sX[n0 + 1][i];
        a00 += x0 * w.x; a01 += x0 * w.y; a02 += x0 * w.z; a03 += x0 * w.w;
        a10 += x1 * w.x; a11 += x1 * w.y; a12 += x1 * w.z; a13 += x1 * w.w;
    }
    int d0 = nodeBase + n0, d1 = d0 + 1;
    if (d0 < NN) { float s = dinv[d0];
        *(float4*)&h1s[(size_t)d0 * H1D + k0] = make_float4(a00 * s, a01 * s, a02 * s, a03 * s); }
    if (d1 < NN) { float s = dinv[d1];
        *(float4*)&h1s[(size_t)d1 * H1D + k0] = make_float4(a10 * s, a11 * s, a12 * s, a13 * s); }
}

// layer-1 aggregate: direct-to-LDS row gathers (global_load_lds, width 16).
// Per wave / super-iter: 8 fire-and-forget instrs stage 64 edge rows (~64 lines
// in flight), one vmcnt(0), then ds_read_b128 + ds_add consume.
__global__ __launch_bounds__(256) void k_agg1(const float* __restrict__ h1s,
                                              const float* __restrict__ dinv,
                                              const int* __restrict__ bcur,
                                              const int* __restrict__ pairs,
                                              const float* __restrict__ W2,
                                              const float* __restrict__ b1,
                                              float* __restrict__ h2s) {
    __shared__ float acc[BK * S1];     // 16.9 KB
    __shared__ float sW2[H1D * H2D];   // 2 KB
    __shared__ float stage[4][2048];   // 8 KB per wave
    int t = threadIdx.x, b = blockIdx.x;
    for (int i = t; i < BK * S1; i += 256) acc[i] = 0.f;
    for (int i = t; i < H1D * H2D; i += 256) sW2[i] = W2[i];
    __syncthreads();
    int cnt = bcur[b] - b * CAP;
    int cnt_pad = (cnt + 255) & ~255;
    const int* pb = pairs + (size_t)b * CAP;
    int wid = t >> 6, lane = t & 63;
    int g = lane >> 3, k4 = lane & 7;   // 8 rows per instr, 8 lanes (=128B) per row
    float* st = stage[wid];
    int pv[8], pn[8];
    int i = 0;
    if (i < cnt_pad) {
#pragma unroll
        for (int u = 0; u < 8; ++u) pv[u] = pb[i + wid * 64 + u * 8 + g];
    }
    while (i < cnt_pad) {
#pragma unroll
        for (int u = 0; u < 8; ++u)
            load_lds16(h1s + (size_t)(pv[u] & 0x1FFFF) * H1D + k4 * 4, &st[u * 256]);
        int inext = i + 256;
        if (inext < cnt_pad) {
#pragma unroll
            for (int u = 0; u < 8; ++u) pn[u] = pb[inext + wid * 64 + u * 8 + g];
        } else {
#pragma unroll
            for (int u = 0; u < 8; ++u) pn[u] = DUMMY;
        }
        asm volatile("s_waitcnt vmcnt(0)" ::: "memory");
#pragma unroll
        for (int u = 0; u < 8; ++u) {
            float4 v = *(float4*)&st[u * 256 + lane * 4];
            float* a = &acc[(pv[u] >> 17) * S1 + k4 * 4];
            atomicAdd(a + 0, v.x); atomicAdd(a + 1, v.y);
            atomicAdd(a + 2, v.z); atomicAdd(a + 3, v.w);
        }
#pragma unroll
        for (int u = 0; u < 8; ++u) pv[u] = pn[u];
        i = inext;
    }
    __syncthreads();
    int nodeBase = b * BK;
    // feat1 = relu((acc + h1s[d]) * dinv[d] + b1)  (in place in LDS)
    for (int idx = t; idx < BK * H1D; idx += 256) {
        int n = idx >> 5, kk = idx & 31;
        int d = nodeBase + n;
        if (d < NN) {
            float dv = dinv[d];
            float v = (acc[n * S1 + kk] + h1s[(size_t)d * H1D + kk]) * dv + b1[kk];
            acc[n * S1 + kk] = fmaxf(v, 0.f);
        }
    }
    __syncthreads();
    // h2s = (feat1 @ W2) * dinv
    for (int idx = t; idx < BK * H2D; idx += 256) {
        int n = idx >> 4, kk = idx & 15;
        int d = nodeBase + n;
        if (d >= NN) continue;
        const float* fr = &acc[n * S1];
        float s = 0.f;
#pragma unroll
        for (int i2 = 0; i2 < H1D; ++i2) s += fr[i2] * sW2[i2 * H2D + kk];
        h2s[(size_t)d * H2D + kk] = s * dinv[d];
    }
}

// layer-2 aggregate via global_load_lds: 16 rows (64B each) per instr,
// 4 instrs = 64 edges per wave per super-iter.
__global__ __launch_bounds__(256) void k_agg2(const float* __restrict__ h2s,
                                              const float* __restrict__ dinv,
                                              const int* __restrict__ bcur,
                                              const int* __restrict__ pairs,
                                              const float* __restrict__ b2,
                                              const float* __restrict__ W3,
                                              const int* __restrict__ batch,
                                              float* gsum) {
    __shared__ float acc[BK * S2];     // 8.7 KB
    __shared__ float stage[4][1024];   // 4 KB per wave
    int t = threadIdx.x, b = blockIdx.x;
    for (int i = t; i < BK * S2; i += 256) acc[i] = 0.f;
    __syncthreads();
    int cnt = bcur[b] - b * CAP;
    int cnt_pad = (cnt + 255) & ~255;
    const int* pb = pairs + (size_t)b * CAP;
    int wid = t >> 6, lane = t & 63;
    int g = lane >> 2, k4 = lane & 3;   // 16 rows per instr, 4 lanes (=64B) per row
    float* st = stage[wid];
    int pv[4], pn[4];
    int i = 0;
    if (i < cnt_pad) {
#pragma unroll
        for (int u = 0; u < 4; ++u) pv[u] = pb[i + wid * 64 + u * 16 + g];
    }
    while (i < cnt_pad) {
#pragma unroll
        for (int u = 0; u < 4; ++u)
            load_lds16(h2s + (size_t)(pv[u] & 0x1FFFF) * H2D + k4 * 4, &st[u * 256]);
        int inext = i + 256;
        if (inext < cnt_pad) {
#pragma unroll
            for (int u = 0; u < 4; ++u) pn[u] = pb[inext + wid * 64 + u * 16 + g];
        } else {
#pragma unroll
            for (int u = 0; u < 4; ++u) pn[u] = DUMMY;
        }
        asm volatile("s_waitcnt vmcnt(0)" ::: "memory");
#pragma unroll
        for (int u = 0; u < 4; ++u) {
            float4 v = *(float4*)&st[u * 256 + lane * 4];
            float* a = &acc[(pv[u] >> 17) * S2 + k4 * 4];
            atomicAdd(a + 0, v.x); atomicAdd(a + 1, v.y);
            atomicAdd(a + 2, v.z); atomicAdd(a + 3, v.w);
        }
#pragma unroll
        for (int u = 0; u < 4; ++u) pv[u] = pn[u];
        i = inext;
    }
    __syncthreads();
    int nodeBase = b * BK;
    for (int idx = t; idx < BK * H2D; idx += 256) {
        int n = idx >> 4, kk = idx & 15;
        int d = nodeBase + n;
        float v = 0.f;
        if (d < NN) {
            float dv = dinv[d];
            float f = (acc[n * S2 + kk] + h2s[(size_t)d * H2D + kk]) * dv + b2[kk];
            v = fmaxf(f, 0.f) * W3[kk];
        }
        v += __shfl_xor(v, 1);
        v += __shfl_xor(v, 2);
        v += __shfl_xor(v, 4);
        v += __shfl_xor(v, 8);
        if (kk == 0 && d < NN) atomicAdd(&gsum[batch[d]], v);
    }
}

__global__ __launch_bounds__(256) void k_final(const float* gsum, const float* gcnt,
                                               const float* b3, float* out) {
    int g = blockIdx.x * 256 + threadIdx.x;
    if (g < NG) out[g] = gsum[g] / fmaxf(gcnt[g], 1.0f) + b3[0];
}

extern "C" void kernel_launch(void* const* d_in, const int* in_sizes, int n_in,
                              void* d_out, int out_size, void* d_ws, size_t ws_size,
                              hipStream_t stream) {
    const float* x     = (const float*)d_in[0];
    const int*   src   = (const int*)d_in[1];
    const int*   dst   = src + NE;
    const int*   batch = (const int*)d_in[2];
    const float* W1 = (const float*)d_in[3];
    const float* b1 = (const float*)d_in[4];
    const float* W2 = (const float*)d_in[5];
    const float* b2 = (const float*)d_in[6];
    const float* W3 = (const float*)d_in[7];
    const float* b3 = (const float*)d_in[8];
    float* out = (float*)d_out;

    float* ws = (float*)d_ws;
    int*   bcur  = (int*)(ws + O_BCUR);
    float* gsum  = ws + O_GSUM;
    float* gcnt  = ws + O_GCNT;
    float* dinv  = ws + O_DINV;
    int*   pairs = (int*)(ws + O_PAIRS);
    float* h1s   = ws + O_H1S;
    float* h2s   = ws + O_H2S;

    k_init <<<4, 256, 0, stream>>>(bcur, gsum, gcnt, h1s, h2s);
    k_stage<<<NBUK, 256, 0, stream>>>(src, dst, bcur, pairs);
    k_deg  <<<NBUK, 256, 0, stream>>>(bcur, pairs, batch, dinv, gcnt);
    k_gemm1<<<(NN + 63) / 64, 256, 0, stream>>>(x, W1, dinv, h1s);
    k_agg1 <<<NBUK, 256, 0, stream>>>(h1s, dinv, bcur, pairs, W2, b1, h2s);
    k_agg2 <<<NBUK, 256, 0, stream>>>(h2s, dinv, bcur, pairs, b2, W3, batch, gsum);
    k_final<<<2, 256, 0, stream>>>(gsum, gcnt, b3, out);
}

// Round 6
// 1346.926 us; speedup vs baseline: 1.0258x; 1.0258x over previous
//
#include <hip/hip_runtime.h>
#include <hip/hip_bf16.h>

#define NN 100000     // nodes
#define NE 3200000    // edges
#define NG 512        // graphs
#define IND 128
#define H1D 32
#define H2D 16

#define BK   128              // nodes per bucket
#define NBUK 782              // ceil(NN/BK)
#define CAP  4864             // slots per bucket (mean 4096; +8 sigma pad room)
#define DUMMY NN              // dummy src row (zeroed); localdst bits = 0
#define S1 33                 // padded LDS stride for H1D rows
#define S2 17                 // padded LDS stride for H2D rows

typedef float vf4 __attribute__((ext_vector_type(4)));
typedef int   vi4 __attribute__((ext_vector_type(4)));

// ---------------- workspace layout (element offsets, 4B each) ----------------
#define O_BCUR  0u            // int[1024]
#define O_GSUM  1024u         // float[512]
#define O_GCNT  1536u         // float[512]
#define O_DINV  2048u         // float[100352]
#define O_PAIRS 102400u       // int[NBUK*CAP = 3,803,648] packed: src | (localdst<<17)
#define O_H1S   3906048u      // float[(NN+1)*32]  h1s = (x@W1)*dinv, +1 dummy row
#define O_H2S   7106080u      // float[(NN+1)*16]  h2s = (feat1@W2)*dinv, +1 dummy row
// total = 8,706,096 elems = 34.8 MB

__global__ __launch_bounds__(256) void k_init(int* bcur, float* gsum, float* gcnt,
                                              float* h1s, float* h2s) {
    int i = blockIdx.x * 256 + threadIdx.x;
    if (i < 1024) bcur[i] = i * CAP;
    if (i < NG) { gsum[i] = 0.f; gcnt[i] = 0.f; }
    if (i < H1D) h1s[(size_t)NN * H1D + i] = 0.f;   // dummy row for padded edges
    if (i < H2D) h2s[(size_t)NN * H2D + i] = 0.f;
}

// Stage edges into per-bucket regions. Tile = 4096 edges per block; LDS binning
// + one bulk cursor atomic per (block,bucket) -> writes are sequential runs.
__global__ __launch_bounds__(256) void k_stage(const int* __restrict__ src,
                                               const int* __restrict__ dst,
                                               int* bcur, int* __restrict__ pairs) {
    __shared__ int cnt[NBUK], pre[NBUK], cur[NBUK], gb[NBUK];
    __shared__ int2 buf[4096];     // (packed, bucket)
    __shared__ int scan[256];
    int t = threadIdx.x;
    for (int i = t; i < NBUK; i += 256) cnt[i] = 0;
    __syncthreads();

    int eb = blockIdx.x * 4096;
    int s16[16], d16[16];
#pragma unroll
    for (int j = 0; j < 16; ++j) {
        int e = eb + j * 256 + t;
        if (e < NE) {
            s16[j] = src[e];
            d16[j] = dst[e];
            atomicAdd(&cnt[d16[j] >> 7], 1);
        } else d16[j] = -1;
    }
    __syncthreads();

    int c0 = (t * 4 + 0 < NBUK) ? cnt[t * 4 + 0] : 0;
    int c1 = (t * 4 + 1 < NBUK) ? cnt[t * 4 + 1] : 0;
    int c2 = (t * 4 + 2 < NBUK) ? cnt[t * 4 + 2] : 0;
    int c3 = (t * 4 + 3 < NBUK) ? cnt[t * 4 + 3] : 0;
    int s4 = c0 + c1 + c2 + c3;
    scan[t] = s4;
    __syncthreads();
    for (int off = 1; off < 256; off <<= 1) {
        int v = (t >= off) ? scan[t - off] : 0;
        __syncthreads();
        scan[t] += v;
        __syncthreads();
    }
    int excl = scan[t] - s4;
    if (t * 4 + 0 < NBUK) pre[t * 4 + 0] = excl;
    if (t * 4 + 1 < NBUK) pre[t * 4 + 1] = excl + c0;
    if (t * 4 + 2 < NBUK) pre[t * 4 + 2] = excl + c0 + c1;
    if (t * 4 + 3 < NBUK) pre[t * 4 + 3] = excl + c0 + c1 + c2;
    __syncthreads();

    for (int i = t; i < NBUK; i += 256) {
        int c = cnt[i];
        gb[i] = c ? atomicAdd(&bcur[i], c) : 0;
        cur[i] = pre[i];
    }
    __syncthreads();

#pragma unroll
    for (int j = 0; j < 16; ++j) {
        if (d16[j] >= 0) {
            int b = d16[j] >> 7;
            int slot = atomicAdd(&cur[b], 1);
            buf[slot] = make_int2(s16[j] | ((d16[j] & 127) << 17), b);
        }
    }
    __syncthreads();

    int tot = scan[255];
    for (int slot = t; slot < tot; slot += 256) {
        int2 e = buf[slot];
        pairs[gb[e.y] + (slot - pre[e.y])] = e.x;
    }
}

// per-bucket degree histogram -> dinv; graph node counts; pad bucket to mult-of-256
__global__ __launch_bounds__(256) void k_deg(const int* __restrict__ bcur,
                                             int* __restrict__ pairs,
                                             const int* __restrict__ batch,
                                             float* __restrict__ dinv,
                                             float* gcnt) {
    __shared__ int hist[BK];
    int t = threadIdx.x, b = blockIdx.x;
    if (t < BK) hist[t] = 0;
    __syncthreads();
    int cnt = bcur[b] - b * CAP;
    int cnt_pad = (cnt + 255) & ~255;
    for (int i = cnt + t; i < cnt_pad; i += 256) pairs[(size_t)b * CAP + i] = DUMMY;
    const int* pb = pairs + (size_t)b * CAP;
    for (int i = t; i < cnt; i += 256) atomicAdd(&hist[pb[i] >> 17], 1);
    __syncthreads();
    if (t < BK) {
        int d = b * BK + t;
        if (d < NN) {
            dinv[d] = rsqrtf((float)(hist[t] + 1));   // +1 self-loop
            atomicAdd(&gcnt[batch[d]], 1.0f);
        }
    }
}

// h1s = (x @ W1) * dinv : register-tiled 2 nodes x 4 k per thread
__global__ __launch_bounds__(256) void k_gemm1(const float* __restrict__ x,
                                               const float* __restrict__ W1,
                                               const float* __restrict__ dinv,
                                               float* __restrict__ h1s) {
    __shared__ float sX[64][IND + 1];
    __shared__ float sW[IND * H1D];
    int t = threadIdx.x;
    int nodeBase = blockIdx.x * 64;
    for (int i = t; i < IND * H1D; i += 256) sW[i] = W1[i];
    for (int i = t; i < 64 * IND / 4; i += 256) {
        int r = i >> 5;
        int c = (i & 31) * 4;
        int d = nodeBase + r;
        float4 v = (d < NN) ? *(const float4*)&x[(size_t)d * IND + c]
                            : make_float4(0.f, 0.f, 0.f, 0.f);
        sX[r][c] = v.x; sX[r][c + 1] = v.y; sX[r][c + 2] = v.z; sX[r][c + 3] = v.w;
    }
    __syncthreads();
    int k0 = (t & 7) * 4;
    int n0 = (t >> 3) * 2;
    float a00 = 0, a01 = 0, a02 = 0, a03 = 0, a10 = 0, a11 = 0, a12 = 0, a13 = 0;
#pragma unroll 4
    for (int i = 0; i < IND; ++i) {
        float4 w = *(const float4*)&sW[i * H1D + k0];
        float x0 = sX[n0][i], x1 = sX[n0 + 1][i];
        a00 += x0 * w.x; a01 += x0 * w.y; a02 += x0 * w.z; a03 += x0 * w.w;
        a10 += x1 * w.x; a11 += x1 * w.y; a12 += x1 * w.z; a13 += x1 * w.w;
    }
    int d0 = nodeBase + n0, d1 = d0 + 1;
    if (d0 < NN) { float s = dinv[d0];
        *(float4*)&h1s[(size_t)d0 * H1D + k0] = make_float4(a00 * s, a01 * s, a02 * s, a03 * s); }
    if (d1 < NN) { float s = dinv[d1];
        *(float4*)&h1s[(size_t)d1 * H1D + k0] = make_float4(a10 * s, a11 * s, a12 * s, a13 * s); }
}

// layer-1 aggregate. ASM-batched gathers: 10 global_load_dwordx4 issued
// back-to-back + ONE s_waitcnt vmcnt(0) -> 64 gather lines in flight per wave.
__global__ __launch_bounds__(256, 3) void k_agg1(const float* __restrict__ h1s,
                                                 const float* __restrict__ dinv,
                                                 const int* __restrict__ bcur,
                                                 const int* __restrict__ pairs,
                                                 const float* __restrict__ W2,
                                                 const float* __restrict__ b1,
                                                 float* __restrict__ h2s) {
    __shared__ float acc[BK * S1];    // 16.9 KB
    __shared__ float sW2[H1D * H2D];  // 2 KB
    int t = threadIdx.x, b = blockIdx.x;
    for (int i = t; i < BK * S1; i += 256) acc[i] = 0.f;
    for (int i = t; i < H1D * H2D; i += 256) sW2[i] = W2[i];
    __syncthreads();
    int cnt = bcur[b] - b * CAP;
    int cnt_pad = (cnt + 255) & ~255;
    const int* pb = pairs + (size_t)b * CAP;
    int k4 = t & 7;          // float4 piece of the 32-float row
    int g  = t >> 3;         // group 0..31; 8 edges per group per iter
    int base = g * 8;
    int coff = k4 * 4;
    vi4 q0 = *(const vi4*)&pb[base];
    vi4 q1 = *(const vi4*)&pb[base + 4];
    int i = 0;
    while (i < cnt_pad) {
        int inext = i + 256;
        int ip = (inext < cnt_pad) ? inext : 0;    // clamp: prefetch stays in-bounds
        const int* pq0 = &pb[ip + base];
        const int* pq1 = pq0 + 4;
        const float* a0 = h1s + (size_t)(q0.x & 0x1FFFF) * H1D + coff;
        const float* a1 = h1s + (size_t)(q0.y & 0x1FFFF) * H1D + coff;
        const float* a2 = h1s + (size_t)(q0.z & 0x1FFFF) * H1D + coff;
        const float* a3 = h1s + (size_t)(q0.w & 0x1FFFF) * H1D + coff;
        const float* a4 = h1s + (size_t)(q1.x & 0x1FFFF) * H1D + coff;
        const float* a5 = h1s + (size_t)(q1.y & 0x1FFFF) * H1D + coff;
        const float* a6 = h1s + (size_t)(q1.z & 0x1FFFF) * H1D + coff;
        const float* a7 = h1s + (size_t)(q1.w & 0x1FFFF) * H1D + coff;
        vf4 r0, r1, r2, r3, r4, r5, r6, r7;
        vi4 qn0, qn1;
        asm volatile(
            "global_load_dwordx4 %8, %18, off\n\t"
            "global_load_dwordx4 %9, %19, off\n\t"
            "global_load_dwordx4 %0, %10, off\n\t"
            "global_load_dwordx4 %1, %11, off\n\t"
            "global_load_dwordx4 %2, %12, off\n\t"
            "global_load_dwordx4 %3, %13, off\n\t"
            "global_load_dwordx4 %4, %14, off\n\t"
            "global_load_dwordx4 %5, %15, off\n\t"
            "global_load_dwordx4 %6, %16, off\n\t"
            "global_load_dwordx4 %7, %17, off\n\t"
            "s_waitcnt vmcnt(0)"
            : "=&v"(r0), "=&v"(r1), "=&v"(r2), "=&v"(r3),
              "=&v"(r4), "=&v"(r5), "=&v"(r6), "=&v"(r7),
              "=&v"(qn0), "=&v"(qn1)
            : "v"(a0), "v"(a1), "v"(a2), "v"(a3),
              "v"(a4), "v"(a5), "v"(a6), "v"(a7),
              "v"(pq0), "v"(pq1));
        float* A;
        A = &acc[(q0.x >> 17) * S1 + coff];
        atomicAdd(A + 0, r0.x); atomicAdd(A + 1, r0.y); atomicAdd(A + 2, r0.z); atomicAdd(A + 3, r0.w);
        A = &acc[(q0.y >> 17) * S1 + coff];
        atomicAdd(A + 0, r1.x); atomicAdd(A + 1, r1.y); atomicAdd(A + 2, r1.z); atomicAdd(A + 3, r1.w);
        A = &acc[(q0.z >> 17) * S1 + coff];
        atomicAdd(A + 0, r2.x); atomicAdd(A + 1, r2.y); atomicAdd(A + 2, r2.z); atomicAdd(A + 3, r2.w);
        A = &acc[(q0.w >> 17) * S1 + coff];
        atomicAdd(A + 0, r3.x); atomicAdd(A + 1, r3.y); atomicAdd(A + 2, r3.z); atomicAdd(A + 3, r3.w);
        A = &acc[(q1.x >> 17) * S1 + coff];
        atomicAdd(A + 0, r4.x); atomicAdd(A + 1, r4.y); atomicAdd(A + 2, r4.z); atomicAdd(A + 3, r4.w);
        A = &acc[(q1.y >> 17) * S1 + coff];
        atomicAdd(A + 0, r5.x); atomicAdd(A + 1, r5.y); atomicAdd(A + 2, r5.z); atomicAdd(A + 3, r5.w);
        A = &acc[(q1.z >> 17) * S1 + coff];
        atomicAdd(A + 0, r6.x); atomicAdd(A + 1, r6.y); atomicAdd(A + 2, r6.z); atomicAdd(A + 3, r6.w);
        A = &acc[(q1.w >> 17) * S1 + coff];
        atomicAdd(A + 0, r7.x); atomicAdd(A + 1, r7.y); atomicAdd(A + 2, r7.z); atomicAdd(A + 3, r7.w);
        q0 = qn0; q1 = qn1;
        i = inext;
    }
    __syncthreads();
    int nodeBase = b * BK;
    // feat1 = relu((acc + h1s[d]) * dinv[d] + b1)  (in place in LDS)
    for (int idx = t; idx < BK * H1D; idx += 256) {
        int n = idx >> 5, kk = idx & 31;
        int d = nodeBase + n;
        if (d < NN) {
            float dv = dinv[d];
            float v = (acc[n * S1 + kk] + h1s[(size_t)d * H1D + kk]) * dv + b1[kk];
            acc[n * S1 + kk] = fmaxf(v, 0.f);
        }
    }
    __syncthreads();
    // h2s = (feat1 @ W2) * dinv
    for (int idx = t; idx < BK * H2D; idx += 256) {
        int n = idx >> 4, kk = idx & 15;
        int d = nodeBase + n;
        if (d >= NN) continue;
        const float* fr = &acc[n * S1];
        float s = 0.f;
#pragma unroll
        for (int i2 = 0; i2 < H1D; ++i2) s += fr[i2] * sW2[i2 * H2D + kk];
        h2s[(size_t)d * H2D + kk] = s * dinv[d];
    }
}

// layer-2 aggregate. ASM-batched: 5 loads + one vmcnt(0); 64 lines/wave in flight.
__global__ __launch_bounds__(256, 3) void k_agg2(const float* __restrict__ h2s,
                                                 const float* __restrict__ dinv,
                                                 const int* __restrict__ bcur,
                                                 const int* __restrict__ pairs,
                                                 const float* __restrict__ b2,
                                                 const float* __restrict__ W3,
                                                 const int* __restrict__ batch,
                                                 float* gsum) {
    __shared__ float acc[BK * S2];   // 8.7 KB
    int t = threadIdx.x, b = blockIdx.x;
    for (int i = t; i < BK * S2; i += 256) acc[i] = 0.f;
    __syncthreads();
    int cnt = bcur[b] - b * CAP;
    int cnt_pad = (cnt + 255) & ~255;
    const int* pb = pairs + (size_t)b * CAP;
    int k4 = t & 3;          // float4 piece of the 16-float row
    int g  = t >> 2;         // group 0..63; 4 edges per group per iter
    int base = g * 4;
    int coff = k4 * 4;
    vi4 q0 = *(const vi4*)&pb[base];
    int i = 0;
    while (i < cnt_pad) {
        int inext = i + 256;
        int ip = (inext < cnt_pad) ? inext : 0;
        const int* pq = &pb[ip + base];
        const float* a0 = h2s + (size_t)(q0.x & 0x1FFFF) * H2D + coff;
        const float* a1 = h2s + (size_t)(q0.y & 0x1FFFF) * H2D + coff;
        const float* a2 = h2s + (size_t)(q0.z & 0x1FFFF) * H2D + coff;
        const float* a3 = h2s + (size_t)(q0.w & 0x1FFFF) * H2D + coff;
        vf4 r0, r1, r2, r3;
        vi4 qn;
        asm volatile(
            "global_load_dwordx4 %4, %9, off\n\t"
            "global_load_dwordx4 %0, %5, off\n\t"
            "global_load_dwordx4 %1, %6, off\n\t"
            "global_load_dwordx4 %2, %7, off\n\t"
            "global_load_dwordx4 %3, %8, off\n\t"
            "s_waitcnt vmcnt(0)"
            : "=&v"(r0), "=&v"(r1), "=&v"(r2), "=&v"(r3), "=&v"(qn)
            : "v"(a0), "v"(a1), "v"(a2), "v"(a3), "v"(pq));
        float* A;
        A = &acc[(q0.x >> 17) * S2 + coff];
        atomicAdd(A + 0, r0.x); atomicAdd(A + 1, r0.y); atomicAdd(A + 2, r0.z); atomicAdd(A + 3, r0.w);
        A = &acc[(q0.y >> 17) * S2 + coff];
        atomicAdd(A + 0, r1.x); atomicAdd(A + 1, r1.y); atomicAdd(A + 2, r1.z); atomicAdd(A + 3, r1.w);
        A = &acc[(q0.z >> 17) * S2 + coff];
        atomicAdd(A + 0, r2.x); atomicAdd(A + 1, r2.y); atomicAdd(A + 2, r2.z); atomicAdd(A + 3, r2.w);
        A = &acc[(q0.w >> 17) * S2 + coff];
        atomicAdd(A + 0, r3.x); atomicAdd(A + 1, r3.y); atomicAdd(A + 2, r3.z); atomicAdd(A + 3, r3.w);
        q0 = qn;
        i = inext;
    }
    __syncthreads();
    int nodeBase = b * BK;
    for (int idx = t; idx < BK * H2D; idx += 256) {
        int n = idx >> 4, kk = idx & 15;
        int d = nodeBase + n;
        float v = 0.f;
        if (d < NN) {
            float dv = dinv[d];
            float f = (acc[n * S2 + kk] + h2s[(size_t)d * H2D + kk]) * dv + b2[kk];
            v = fmaxf(f, 0.f) * W3[kk];
        }
        v += __shfl_xor(v, 1);
        v += __shfl_xor(v, 2);
        v += __shfl_xor(v, 4);
        v += __shfl_xor(v, 8);
        if (kk == 0 && d < NN) atomicAdd(&gsum[batch[d]], v);
    }
}

__global__ __launch_bounds__(256) void k_final(const float* gsum, const float* gcnt,
                                               const float* b3, float* out) {
    int g = blockIdx.x * 256 + threadIdx.x;
    if (g < NG) out[g] = gsum[g] / fmaxf(gcnt[g], 1.0f) + b3[0];
}

extern "C" void kernel_launch(void* const* d_in, const int* in_sizes, int n_in,
                              void* d_out, int out_size, void* d_ws, size_t ws_size,
                              hipStream_t stream) {
    const float* x     = (const float*)d_in[0];
    const int*   src   = (const int*)d_in[1];
    const int*   dst   = src + NE;
    const int*   batch = (const int*)d_in[2];
    const float* W1 = (const float*)d_in[3];
    const float* b1 = (const float*)d_in[4];
    const float* W2 = (const float*)d_in[5];
    const float* b2 = (const float*)d_in[6];
    const float* W3 = (const float*)d_in[7];
    const float* b3 = (const float*)d_in[8];
    float* out = (float*)d_out;

    float* ws = (float*)d_ws;
    int*   bcur  = (int*)(ws + O_BCUR);
    float* gsum  = ws + O_GSUM;
    float* gcnt  = ws + O_GCNT;
    float* dinv  = ws + O_DINV;
    int*   pairs = (int*)(ws + O_PAIRS);
    float* h1s   = ws + O_H1S;
    float* h2s   = ws + O_H2S;

    k_init <<<4, 256, 0, stream>>>(bcur, gsum, gcnt, h1s, h2s);
    k_stage<<<NBUK, 256, 0, stream>>>(src, dst, bcur, pairs);
    k_deg  <<<NBUK, 256, 0, stream>>>(bcur, pairs, batch, dinv, gcnt);
    k_gemm1<<<(NN + 63) / 64, 256, 0, stream>>>(x, W1, dinv, h1s);
    k_agg1 <<<NBUK, 256, 0, stream>>>(h1s, dinv, bcur, pairs, W2, b1, h2s);
    k_agg2 <<<NBUK, 256, 0, stream>>>(h2s, dinv, bcur, pairs, b2, W3, batch, gsum);
    k_final<<<2, 256, 0, stream>>>(gsum, gcnt, b3, out);
}